// Round 14
// baseline (530.378 us; speedup 1.0000x reference)
//
#include <hip/hip_runtime.h>

typedef __attribute__((ext_vector_type(8))) short short8;
typedef __attribute__((ext_vector_type(4))) float f32x4;

constexpr int N = 100000;
constexpr int E = 1600000;
constexpr int F = 128;
constexpr float EPS = 1e-5f;
constexpr int NB = (N + 1023) / 1024;  // 98 scan blocks

// partitioned counting-sort geometry
constexpr int R_RNG = 16;
constexpr int BINS = 6250;           // R_RNG*BINS == N exactly
constexpr int G2 = 64;               // blocks per range in hist2/scatter3
constexpr int NPB = 640;             // partition blocks
constexpr int EPB = E / NPB;         // 2500 edges per partition block
constexpr int EPB4 = EPB / 4;        // 625 int4 per partition block

// ---- bf16 split helpers (RNE) ----
__device__ __forceinline__ short bf16hi(float v) {
  unsigned u = __float_as_uint(v);
  unsigned r = (u + 0x7fffu + ((u >> 16) & 1u)) >> 16;
  return (short)r;
}
__device__ __forceinline__ float bf16f(short h) {
  return __uint_as_float(((unsigned)(unsigned short)h) << 16);
}
__device__ __forceinline__ float bflo(unsigned v) {
  return __uint_as_float(v << 16);
}
__device__ __forceinline__ float bfhi(unsigned v) {
  return __uint_as_float(v & 0xffff0000u);
}

// ---------------- phase A: per-block 16-range histogram + block-local prefix ----
__global__ __launch_bounds__(256) void k_phist(const int* __restrict__ ei, int* __restrict__ Psl) {
  __shared__ int h16[16];
  const int b = blockIdx.x;
  const int tid = threadIdx.x;
  if (tid < 16) h16[tid] = 0;
  __syncthreads();
  const int4* cols4 = (const int4*)(ei + E);
  for (int t = tid; t < EPB4; t += 256) {
    int4 c = cols4[b * EPB4 + t];
    atomicAdd(&h16[c.x / BINS], 1);
    atomicAdd(&h16[c.y / BINS], 1);
    atomicAdd(&h16[c.z / BINS], 1);
    atomicAdd(&h16[c.w / BINS], 1);
  }
  __syncthreads();
  if (tid == 0) {
    int run = 0;
#pragma unroll
    for (int r = 0; r < 16; ++r) { Psl[b * 17 + r] = run; run += h16[r]; }
    Psl[b * 17 + 16] = run;  // == EPB
  }
}

// ---------------- phase C: partition edges into per-(block,range) slices ----
__global__ __launch_bounds__(256) void k_pscatter(const int* __restrict__ ei, const float* __restrict__ ew,
                                                  const int* __restrict__ Psl, int2* __restrict__ pe) {
  __shared__ int cur[16];
  const int b = blockIdx.x;
  const int tid = threadIdx.x;
  if (tid < 16) cur[tid] = Psl[b * 17 + tid];
  __syncthreads();
  const int4* cols4 = (const int4*)(ei + E);
  const int4* rows4 = (const int4*)ei;
  const float4* ew4 = (const float4*)ew;
  const int base = b * EPB;
  for (int t = tid; t < EPB4; t += 256) {
    int4 c = cols4[b * EPB4 + t];
    int4 rr = rows4[b * EPB4 + t];
    float4 w = ew4[b * EPB4 + t];
#pragma unroll
    for (int j = 0; j < 4; ++j) {
      int cc = (j == 0) ? c.x : (j == 1) ? c.y : (j == 2) ? c.z : c.w;
      int rv = (j == 0) ? rr.x : (j == 1) ? rr.y : (j == 2) ? rr.z : rr.w;
      float wv = (j == 0) ? w.x : (j == 1) ? w.y : (j == 2) ? w.z : w.w;
      int r = cc / BINS;
      int pos = base + atomicAdd(&cur[r], 1);
      pe[pos] = make_int2((rv << 13) | (cc - r * BINS), __float_as_int(wv));
    }
  }
}

// ---------------- phase D: per-(range,g) bin histogram over owned slices ----
__global__ __launch_bounds__(256) void k_hist2(const int2* __restrict__ pe, const int* __restrict__ Psl,
                                               int* __restrict__ P) {
  __shared__ int hist[BINS];
  const int r = blockIdx.x / G2;
  const int g = blockIdx.x % G2;
  const int tid = threadIdx.x;
  for (int i = tid; i < BINS; i += 256) hist[i] = 0;
  __syncthreads();
  for (int b = g; b < NPB; b += G2) {
    const int s = Psl[b * 17 + r], e2 = Psl[b * 17 + r + 1];
    const int eb = b * EPB;
    for (int t = s + tid; t < e2; t += 256)
      atomicAdd(&hist[pe[eb + t].x & 0x1FFF], 1);
  }
  __syncthreads();
  for (int i = tid; i < BINS; i += 256) P[(size_t)blockIdx.x * BINS + i] = hist[i];
}

// phase D2: per-bin total -> cnt; P becomes exclusive prefix over g (in place)
__global__ __launch_bounds__(256) void k_reduce(int* __restrict__ P, int* __restrict__ cnt) {
  int b = blockIdx.x * 256 + threadIdx.x;
  if (b >= N) return;
  int r = b / BINS, lb = b % BINS;
  size_t base = (size_t)r * G2 * BINS + lb;
  int run = 0;
#pragma unroll 4
  for (int g = 0; g < G2; ++g) {
    size_t idx = base + (size_t)g * BINS;
    int v = P[idx];
    P[idx] = run;
    run += v;
  }
  cnt[b] = run;
}

__global__ __launch_bounds__(256) void k_bsum(const int* __restrict__ cnt, int* __restrict__ bsum) {
  __shared__ int sh[256];
  int base = blockIdx.x * 1024 + threadIdx.x * 4;
  int s = 0;
  if (base + 3 < N) {
    int4 v = *(const int4*)&cnt[base];
    s = v.x + v.y + v.z + v.w;
  } else {
#pragma unroll
    for (int j = 0; j < 4; ++j)
      if (base + j < N) s += cnt[base + j];
  }
  sh[threadIdx.x] = s;
  __syncthreads();
  for (int o = 128; o > 0; o >>= 1) {
    if (threadIdx.x < o) sh[threadIdx.x] += sh[threadIdx.x + o];
    __syncthreads();
  }
  if (threadIdx.x == 0) bsum[blockIdx.x] = sh[0];
}

__global__ __launch_bounds__(128) void k_bscan(const int* __restrict__ bsum, int* __restrict__ bbase,
                                               int* __restrict__ offN) {
  __shared__ int sh[128];
  const int t = threadIdx.x;
  int v = (t < NB) ? bsum[t] : 0;
  sh[t] = v;
  __syncthreads();
  for (int o = 1; o < 128; o <<= 1) {
    int u = (t >= o) ? sh[t - o] : 0;
    __syncthreads();
    sh[t] += u;
    __syncthreads();
  }
  if (t < NB) bbase[t] = sh[t] - v;
  if (t == 127) *offN = sh[127];
}

__global__ __launch_bounds__(256) void k_off(const int* __restrict__ cnt, const int* __restrict__ bbase,
                                             int* __restrict__ off) {
  __shared__ int sh[256];
  int base = blockIdx.x * 1024 + threadIdx.x * 4;
  int c[4] = {0, 0, 0, 0};
  if (base + 3 < N) {
    int4 v = *(const int4*)&cnt[base];
    c[0] = v.x; c[1] = v.y; c[2] = v.z; c[3] = v.w;
  } else {
#pragma unroll
    for (int j = 0; j < 4; ++j)
      if (base + j < N) c[j] = cnt[base + j];
  }
  int s = c[0] + c[1] + c[2] + c[3];
  sh[threadIdx.x] = s;
  __syncthreads();
  for (int o = 1; o < 256; o <<= 1) {
    int u = (threadIdx.x >= o) ? sh[threadIdx.x - o] : 0;
    __syncthreads();
    sh[threadIdx.x] += u;
    __syncthreads();
  }
  int run = bbase[blockIdx.x] + sh[threadIdx.x] - s;
#pragma unroll
  for (int j = 0; j < 4; ++j) {
    if (base + j < N) { off[base + j] = run; run += c[j]; }
  }
}

// ---------------- phase F: scatter to CSC as packed {row, weight} ----
__global__ __launch_bounds__(256) void k_scatter3(const int2* __restrict__ pe, const int* __restrict__ Psl,
                                                  const int* __restrict__ off, const int* __restrict__ P,
                                                  int2* __restrict__ cpair) {
  __shared__ int base[BINS];
  const int r = blockIdx.x / G2;
  const int g = blockIdx.x % G2;
  const int tid = threadIdx.x;
  for (int i = tid; i < BINS; i += 256)
    base[i] = off[r * BINS + i] + P[(size_t)blockIdx.x * BINS + i];
  __syncthreads();
  for (int b = g; b < NPB; b += G2) {
    const int s = Psl[b * 17 + r], e2 = Psl[b * 17 + r + 1];
    const int eb = b * EPB;
    for (int t = s + tid; t < e2; t += 256) {
      int2 p = pe[eb + t];
      int pos = atomicAdd(&base[p.x & 0x1FFF], 1);
      cpair[pos] = make_int2((int)(((unsigned)p.x) >> 13), p.y);
    }
  }
}

__global__ __launch_bounds__(256) void k_degcsc(const int2* __restrict__ cpair, const int* __restrict__ off,
                                                float* __restrict__ dinv) {
  int i = blockIdx.x * 256 + threadIdx.x;
  if (i >= N) return;
  int b = off[i], e2 = off[i + 1];
  float s = 1.0f;
  for (int p = b; p < e2; ++p) s += __int_as_float(cpair[p].y);
  dinv[i] = rsqrtf(s);
}

// normalize + pack to 4B: (row<<15) | (bf16bits(w) & 0x7FFF)   [w > 0 always]
__global__ __launch_bounds__(256) void k_nrm(const int* __restrict__ off,
                                             const float* __restrict__ dinv,
                                             const int2* __restrict__ cpair,
                                             unsigned* __restrict__ cp4) {
  int i = blockIdx.x * 256 + threadIdx.x;
  if (i >= N) return;
  int b = off[i], e2 = off[i + 1];
  float di = dinv[i];
  for (int p = b; p < e2; ++p) {
    int2 cp = cpair[p];
    float w = dinv[cp.x] * __int_as_float(cp.y) * di;
    unsigned wb = (unsigned)(unsigned short)bf16hi(w);
    cp4[p] = ((unsigned)cp.x << 15) | (wb & 0x7FFFu);
  }
}

// ---- W prep (all 3 mats) + zero BN stats buffers: one dispatch ----
__global__ __launch_bounds__(256) void k_wprep_all(
    const float* __restrict__ W1, const float* __restrict__ W2, const float* __restrict__ Wf1,
    short* __restrict__ wt1h, short* __restrict__ wt1l,
    short* __restrict__ wt2h, short* __restrict__ wt2l,
    short* __restrict__ wtfh, short* __restrict__ wtfl,
    float* __restrict__ st1, float* __restrict__ st2) {
  int idx = blockIdx.x * 256 + threadIdx.x;
  if (idx < 256) st1[idx] = 0.f;
  else if (idx < 512) st2[idx - 256] = 0.f;
  const float* W;
  short *wh, *wl;
  int K, li;
  if (idx < 16384)      { W = W1;  wh = wt1h; wl = wt1l; K = 128; li = idx; }
  else if (idx < 32768) { W = W2;  wh = wt2h; wl = wt2l; K = 128; li = idx - 16384; }
  else if (idx < 81920) { W = Wf1; wh = wtfh; wl = wtfl; K = 384; li = idx - 32768; }
  else return;
  int k = li >> 7, c = li & 127;
  float v = W[(size_t)k * 128 + c];
  short h = bf16hi(v);
  short l = bf16hi(v - bf16f(h));
  wh[(size_t)c * K + k] = h;
  wl[(size_t)c * K + k] = l;
}

// ---- BN params ----
__global__ void k_bnparam(const float* __restrict__ st, const float* __restrict__ gamma,
                          const float* __restrict__ beta, float* __restrict__ p) {
  int t = threadIdx.x;
  if (t >= 128) return;
  const float inv_n = 1.0f / (float)N;
  float m = st[t] * inv_n;
  float var = fmaf(-m, m, st[128 + t] * inv_n);
  float sc = gamma[t] * rsqrtf(var + EPS);
  p[t] = sc;
  p[128 + t] = fmaf(-m, sc, beta[t]);
}

// ---------------- MFMA GEMM with split-bf16 precision ----------------
// OBF16: bf16 output. FC2: fuse final 128->1 dot. AMASK bit s: segment s A is bf16.
template <int KSTEPS, bool OBF16, bool FC2, int AMASK>
__global__ __launch_bounds__(256) void k_gemm_mfma(
    const void* __restrict__ a0, const float* __restrict__ p0,
    const void* __restrict__ a1, const float* __restrict__ p1,
    const void* __restrict__ a2, const float* __restrict__ p2,
    const short* __restrict__ wth, const short* __restrict__ wtl,
    const float* __restrict__ bias, void* __restrict__ Cout,
    const float* __restrict__ wf2, const float* __restrict__ bf2) {
  constexpr int KT = KSTEPS * 32;
  __shared__ short Ah[128][40];
  __shared__ short Al[128][40];
  __shared__ short Bh[128][40];
  __shared__ short Bl[128][40];
  __shared__ float red[2][128];

  const int tid = threadIdx.x;
  const int m0 = blockIdx.x * 128;
  const int sr = tid >> 1;
  const int sk = (tid & 1) * 16;
  const int arow = min(m0 + sr, N - 1);
  const int lane = tid & 63;
  const int lr = lane & 15;
  const int lg = lane >> 4;
  const int wv = tid >> 6;
  const int wr = wv >> 1;
  const int wc = wv & 1;

  f32x4 acc[4][4];
#pragma unroll
  for (int m = 0; m < 4; ++m)
#pragma unroll
    for (int n = 0; n < 4; ++n) acc[m][n] = (f32x4){0.f, 0.f, 0.f, 0.f};

  for (int ks = 0; ks < KSTEPS; ++ks) {
    const int seg = ks >> 2;
    const int koff = (ks & 3) * 32;
    const void* __restrict__ Av = (seg == 0) ? a0 : ((seg == 1) ? a1 : a2);
    const float* __restrict__ P = (seg == 0) ? p0 : ((seg == 1) ? p1 : p2);
    const bool isbf = (AMASK >> seg) & 1;

    float v[16];
    if (isbf) {
      const unsigned short* A16 = (const unsigned short*)Av;
      const uint4* s16 = (const uint4*)&A16[(size_t)arow * F + koff + sk];
      uint4 ua = s16[0], ub = s16[1];
      unsigned uu[8] = {ua.x, ua.y, ua.z, ua.w, ub.x, ub.y, ub.z, ub.w};
#pragma unroll
      for (int j = 0; j < 8; ++j) {
        v[2 * j] = bflo(uu[j]);
        v[2 * j + 1] = bfhi(uu[j]);
      }
    } else {
      const float* A = (const float*)Av;
      const float4* src = (const float4*)(A + (size_t)arow * F + koff + sk);
#pragma unroll
      for (int q = 0; q < 4; ++q) {
        float4 t = src[q];
        v[q * 4 + 0] = t.x; v[q * 4 + 1] = t.y; v[q * 4 + 2] = t.z; v[q * 4 + 3] = t.w;
      }
    }
    if (P) {
      const int c0 = koff + sk;
#pragma unroll
      for (int q = 0; q < 4; ++q) {
        float4 s = *(const float4*)&P[c0 + q * 4];
        float4 b = *(const float4*)&P[128 + c0 + q * 4];
        v[q * 4 + 0] = fmaf(v[q * 4 + 0], s.x, b.x);
        v[q * 4 + 1] = fmaf(v[q * 4 + 1], s.y, b.y);
        v[q * 4 + 2] = fmaf(v[q * 4 + 2], s.z, b.z);
        v[q * 4 + 3] = fmaf(v[q * 4 + 3], s.w, b.w);
      }
    }
    short hh[16], ll[16];
#pragma unroll
    for (int j = 0; j < 16; ++j) {
      hh[j] = bf16hi(v[j]);
      ll[j] = bf16hi(v[j] - bf16f(hh[j]));
    }

    __syncthreads();

    short8 t0, t1, u0, u1;
#pragma unroll
    for (int j = 0; j < 8; ++j) { t0[j] = hh[j]; t1[j] = hh[8 + j]; u0[j] = ll[j]; u1[j] = ll[8 + j]; }
    *(short8*)&Ah[sr][sk] = t0;
    *(short8*)&Ah[sr][sk + 8] = t1;
    *(short8*)&Al[sr][sk] = u0;
    *(short8*)&Al[sr][sk + 8] = u1;

    const size_t wbase = (size_t)sr * KT + ks * 32 + sk;  // global k
    *(short8*)&Bh[sr][sk]     = *(const short8*)&wth[wbase];
    *(short8*)&Bh[sr][sk + 8] = *(const short8*)&wth[wbase + 8];
    *(short8*)&Bl[sr][sk]     = *(const short8*)&wtl[wbase];
    *(short8*)&Bl[sr][sk + 8] = *(const short8*)&wtl[wbase + 8];

    __syncthreads();

    short8 afh[4], afl[4], bfh[4], bfl[4];
#pragma unroll
    for (int m = 0; m < 4; ++m) {
      const int r2 = wr * 64 + m * 16 + lr;
      afh[m] = *(const short8*)&Ah[r2][lg * 8];
      afl[m] = *(const short8*)&Al[r2][lg * 8];
    }
#pragma unroll
    for (int n = 0; n < 4; ++n) {
      const int c2 = wc * 64 + n * 16 + lr;
      bfh[n] = *(const short8*)&Bh[c2][lg * 8];
      bfl[n] = *(const short8*)&Bl[c2][lg * 8];
    }
#pragma unroll
    for (int m = 0; m < 4; ++m)
#pragma unroll
      for (int n = 0; n < 4; ++n) {
        acc[m][n] = __builtin_amdgcn_mfma_f32_16x16x32_bf16(afh[m], bfh[n], acc[m][n], 0, 0, 0);
        acc[m][n] = __builtin_amdgcn_mfma_f32_16x16x32_bf16(afl[m], bfh[n], acc[m][n], 0, 0, 0);
        acc[m][n] = __builtin_amdgcn_mfma_f32_16x16x32_bf16(afh[m], bfl[n], acc[m][n], 0, 0, 0);
      }
  }

  float bv[4];
#pragma unroll
  for (int n = 0; n < 4; ++n) bv[n] = bias ? bias[wc * 64 + n * 16 + lr] : 0.f;

  if (FC2) {
    float w2v[4];
#pragma unroll
    for (int n = 0; n < 4; ++n) w2v[n] = wf2[wc * 64 + n * 16 + lr];
#pragma unroll
    for (int m = 0; m < 4; ++m) {
#pragma unroll
      for (int j = 0; j < 4; ++j) {
        float partial = 0.f;
#pragma unroll
        for (int n = 0; n < 4; ++n)
          partial += fmaxf(acc[m][n][j] + bv[n], 0.f) * w2v[n];
#pragma unroll
        for (int o = 8; o >= 1; o >>= 1) partial += __shfl_xor(partial, o, 16);
        if (lr == 0) red[wc][wr * 64 + m * 16 + lg * 4 + j] = partial;
      }
    }
    __syncthreads();
    if (tid < 128) {
      const int row = m0 + tid;
      if (row < N) {
        float s = red[0][tid] + red[1][tid] + bf2[0];
        ((float*)Cout)[row] = fmaxf(s, 0.f);
      }
    }
  } else {
#pragma unroll
    for (int m = 0; m < 4; ++m) {
#pragma unroll
      for (int j = 0; j < 4; ++j) {
        const int row = m0 + wr * 64 + m * 16 + lg * 4 + j;
        if (row < N) {
#pragma unroll
          for (int n = 0; n < 4; ++n) {
            const int col = wc * 64 + n * 16 + lr;
            float o = acc[m][n][j] + bv[n];
            if (bias) o = fmaxf(o, 0.f);
            if (OBF16) {
              ((unsigned short*)Cout)[(size_t)row * F + col] = (unsigned short)bf16hi(o);
            } else {
              ((float*)Cout)[(size_t)row * F + col] = o;
            }
          }
        }
      }
    }
  }
}

// ---------------- aggregation: col-half x XCD split ----------------
// 50000 blocks; xcd=bid&7 -> half=xcd>>2 (XCDs 0-3: cols 0-63, XCDs 4-7: cols 64-127).
// Wave = one node-half, 1 col/lane (ushort), 8 gathers in flight, packed 4B CSC entries.
__global__ __launch_bounds__(256) void k_agg(
    const unsigned short* __restrict__ h,  // bf16 [N][128]
    const unsigned* __restrict__ cp4, const int* __restrict__ off,
    const float* __restrict__ dinv, const float* __restrict__ bias,
    unsigned short* __restrict__ out) {
  const int bid = blockIdx.x;
  const int xcd = bid & 7;
  const int half = xcd >> 2;
  const int i = ((bid >> 3) * 4 + (xcd & 3)) * 4 + (threadIdx.x >> 6);
  const int lane = threadIdx.x & 63;
  const int co = half * 64 + lane;
  const float di = dinv[i];
  float acc = di * di * bf16f((short)h[(size_t)i * F + co]);
  int e = off[i];
  const int eend = off[i + 1];
  for (; e + 8 <= eend; e += 8) {
    unsigned u[8];
    unsigned short v[8];
#pragma unroll
    for (int j = 0; j < 8; ++j) u[j] = cp4[e + j];
#pragma unroll
    for (int j = 0; j < 8; ++j) v[j] = h[(size_t)(u[j] >> 15) * F + co];
#pragma unroll
    for (int j = 0; j < 8; ++j) {
      float w = __uint_as_float((u[j] & 0x7FFFu) << 16);
      acc = fmaf(w, bf16f((short)v[j]), acc);
    }
  }
  for (; e < eend; ++e) {
    unsigned u = cp4[e];
    float w = __uint_as_float((u & 0x7FFFu) << 16);
    acc = fmaf(w, bf16f((short)h[(size_t)(u >> 15) * F + co]), acc);
  }
  float o = fmaxf(acc + bias[co], 0.f);
  out[(size_t)i * F + co] = (unsigned short)bf16hi(o);
}

// ---------------- BN stats over packed-bf16 h ----------------
__global__ __launch_bounds__(256) void k_stats(const unsigned* __restrict__ h2, float* __restrict__ sums) {
  const int cp = threadIdx.x & 63;   // column pair {2cp, 2cp+1}
  const int q = threadIdx.x >> 6;    // row quarter
  float s0 = 0.f, s1 = 0.f, q0 = 0.f, q1 = 0.f;
  for (int r = blockIdx.x * 4 + q; r < N; r += gridDim.x * 4) {
    unsigned u = h2[(size_t)r * 64 + cp];
    float lo = bflo(u), hi = bfhi(u);
    s0 += lo; s1 += hi;
    q0 = fmaf(lo, lo, q0);
    q1 = fmaf(hi, hi, q1);
  }
  __shared__ float2 sh[256];
  sh[threadIdx.x] = make_float2(s0, s1);
  __syncthreads();
  if (q == 0) {
    float2 a = sh[cp], b = sh[64 + cp], c = sh[128 + cp], d = sh[192 + cp];
    atomicAdd(&sums[2 * cp], a.x + b.x + c.x + d.x);
    atomicAdd(&sums[2 * cp + 1], a.y + b.y + c.y + d.y);
  }
  __syncthreads();
  sh[threadIdx.x] = make_float2(q0, q1);
  __syncthreads();
  if (q == 0) {
    float2 a = sh[cp], b = sh[64 + cp], c = sh[128 + cp], d = sh[192 + cp];
    atomicAdd(&sums[128 + 2 * cp], a.x + b.x + c.x + d.x);
    atomicAdd(&sums[128 + 2 * cp + 1], a.y + b.y + c.y + d.y);
  }
}

extern "C" void kernel_launch(void* const* d_in, const int* in_sizes, int n_in,
                              void* d_out, int out_size, void* d_ws, size_t ws_size,
                              hipStream_t stream) {
  const float* x   = (const float*)d_in[0];
  const int*   ei  = (const int*)d_in[1];
  const float* ew  = (const float*)d_in[2];
  const float* W1  = (const float*)d_in[3];
  const float* b1  = (const float*)d_in[4];
  const float* W2  = (const float*)d_in[5];
  const float* b2  = (const float*)d_in[6];
  const float* g1  = (const float*)d_in[7];
  const float* be1 = (const float*)d_in[8];
  const float* g2  = (const float*)d_in[9];
  const float* be2 = (const float*)d_in[10];
  const float* Wf1 = (const float*)d_in[11];
  const float* bf1 = (const float*)d_in[12];
  const float* Wf2 = (const float*)d_in[13];
  const float* bf2 = (const float*)d_in[14];
  float* out = (float*)d_out;

  char* p = (char*)d_ws;
  auto take = [&](size_t bytes) {
    char* r = p;
    p += (bytes + 255) & ~(size_t)255;
    return r;
  };
  float* st1  = (float*)take(256 * 4);
  float* st2  = (float*)take(256 * 4);
  int*   cnt  = (int*)take((size_t)N * 4);
  int*   off  = (int*)take((size_t)(N + 1) * 4);
  int*   bsum = (int*)take((size_t)NB * 4);
  int*   bbase= (int*)take((size_t)NB * 4);
  int*   Psl  = (int*)take((size_t)NPB * 17 * 4);
  int2*  pe   = (int2*)take((size_t)E * 8);
  int*   Phist= (int*)take((size_t)R_RNG * G2 * BINS * 4);
  float* dinv = (float*)take((size_t)N * 4);
  float* p1   = (float*)take(256 * 4);
  float* p2   = (float*)take(256 * 4);
  short* wt1h = (short*)take((size_t)128 * 128 * 2);
  short* wt1l = (short*)take((size_t)128 * 128 * 2);
  short* wt2h = (short*)take((size_t)128 * 128 * 2);
  short* wt2l = (short*)take((size_t)128 * 128 * 2);
  short* wtfh = (short*)take((size_t)128 * 384 * 2);
  short* wtfl = (short*)take((size_t)128 * 384 * 2);
  int2*  cpair= (int2*)take((size_t)E * 8);
  unsigned* cp4 = (unsigned*)take((size_t)E * 4);
  unsigned short* bufH  = (unsigned short*)take((size_t)N * F * 2);  // conv out (gathered)
  unsigned short* bufB16= (unsigned short*)take((size_t)N * F * 2);  // h1 bf16
  unsigned short* bufC16= (unsigned short*)take((size_t)N * F * 2);  // h2 bf16

  // W prep + BN-stats zeroing
  k_wprep_all<<<320, 256, 0, stream>>>(W1, W2, Wf1, wt1h, wt1l, wt2h, wt2l, wtfh, wtfl, st1, st2);

  // partition-based atomic-free CSC build
  k_phist<<<NPB, 256, 0, stream>>>(ei, Psl);
  k_pscatter<<<NPB, 256, 0, stream>>>(ei, ew, Psl, pe);
  k_hist2<<<R_RNG * G2, 256, 0, stream>>>(pe, Psl, Phist);
  k_reduce<<<(N + 255) / 256, 256, 0, stream>>>(Phist, cnt);
  k_bsum<<<NB, 256, 0, stream>>>(cnt, bsum);
  k_bscan<<<1, 128, 0, stream>>>(bsum, bbase, &off[N]);
  k_off<<<NB, 256, 0, stream>>>(cnt, bbase, off);
  k_scatter3<<<R_RNG * G2, 256, 0, stream>>>(pe, Psl, off, Phist, cpair);
  k_degcsc<<<(N + 255) / 256, 256, 0, stream>>>(cpair, off, dinv);
  k_nrm<<<(N + 255) / 256, 256, 0, stream>>>(off, dinv, cpair, cp4);

  const int gemm_grid = (N + 127) / 128;
  const int agg_grid = (N / 4) * 2;  // 50000: col-half x XCD split
  // conv1: bufH(bf16) = x @ W1
  k_gemm_mfma<4, true, false, 0><<<gemm_grid, 256, 0, stream>>>(
      x, nullptr, nullptr, nullptr, nullptr, nullptr, wt1h, wt1l, nullptr, bufH, nullptr, nullptr);
  k_agg<<<agg_grid, 256, 0, stream>>>(bufH, cp4, off, dinv, b1, bufB16);
  k_stats<<<256, 256, 0, stream>>>((const unsigned*)bufB16, st1);
  k_bnparam<<<1, 128, 0, stream>>>(st1, g1, be1, p1);
  // conv2: bufH(bf16) = bn1(h1_bf16) @ W2   (A is bf16)
  k_gemm_mfma<4, true, false, 1><<<gemm_grid, 256, 0, stream>>>(
      bufB16, p1, nullptr, nullptr, nullptr, nullptr, wt2h, wt2l, nullptr, bufH, nullptr, nullptr);
  k_agg<<<agg_grid, 256, 0, stream>>>(bufH, cp4, off, dinv, b2, bufC16);
  k_stats<<<256, 256, 0, stream>>>((const unsigned*)bufC16, st2);
  k_bnparam<<<1, 128, 0, stream>>>(st2, g2, be2, p2);
  // fc1 + fused fc2 over [x | bn1(h1) | bn2(h2)] -> out[N]  (segs 1,2 bf16)
  k_gemm_mfma<12, false, true, 6><<<gemm_grid, 256, 0, stream>>>(
      x, nullptr, bufB16, p1, bufC16, p2, wtfh, wtfl, bf1, out, Wf2, bf2);
}

// Round 15
// 434.386 us; speedup vs baseline: 1.2210x; 1.2210x over previous
//
#include <hip/hip_runtime.h>

typedef __attribute__((ext_vector_type(8))) short short8;
typedef __attribute__((ext_vector_type(4))) float f32x4;

constexpr int N = 100000;
constexpr int E = 1600000;
constexpr int F = 128;
constexpr float EPS = 1e-5f;
constexpr int NB = (N + 1023) / 1024;  // 98 scan blocks

// partitioned counting-sort geometry
constexpr int R_RNG = 16;
constexpr int BINS = 6250;           // R_RNG*BINS == N exactly
constexpr int G2 = 64;               // blocks per range in hist2/scatter3
constexpr int NPB = 640;             // partition blocks
constexpr int EPB = E / NPB;         // 2500 edges per partition block
constexpr int EPB4 = EPB / 4;        // 625 int4 per partition block

// ---- bf16 split helpers (RNE) ----
__device__ __forceinline__ short bf16hi(float v) {
  unsigned u = __float_as_uint(v);
  unsigned r = (u + 0x7fffu + ((u >> 16) & 1u)) >> 16;
  return (short)r;
}
__device__ __forceinline__ float bf16f(short h) {
  return __uint_as_float(((unsigned)(unsigned short)h) << 16);
}
__device__ __forceinline__ float bflo(unsigned v) {
  return __uint_as_float(v << 16);
}
__device__ __forceinline__ float bfhi(unsigned v) {
  return __uint_as_float(v & 0xffff0000u);
}

// ---------------- phase A: per-block 16-range histogram + block-local prefix ----
__global__ __launch_bounds__(256) void k_phist(const int* __restrict__ ei, int* __restrict__ Psl) {
  __shared__ int h16[16];
  const int b = blockIdx.x;
  const int tid = threadIdx.x;
  if (tid < 16) h16[tid] = 0;
  __syncthreads();
  const int4* cols4 = (const int4*)(ei + E);
  for (int t = tid; t < EPB4; t += 256) {
    int4 c = cols4[b * EPB4 + t];
    atomicAdd(&h16[c.x / BINS], 1);
    atomicAdd(&h16[c.y / BINS], 1);
    atomicAdd(&h16[c.z / BINS], 1);
    atomicAdd(&h16[c.w / BINS], 1);
  }
  __syncthreads();
  if (tid == 0) {
    int run = 0;
#pragma unroll
    for (int r = 0; r < 16; ++r) { Psl[b * 17 + r] = run; run += h16[r]; }
    Psl[b * 17 + 16] = run;  // == EPB
  }
}

// ---------------- phase C: partition edges into per-(block,range) slices ----
__global__ __launch_bounds__(256) void k_pscatter(const int* __restrict__ ei, const float* __restrict__ ew,
                                                  const int* __restrict__ Psl, int2* __restrict__ pe) {
  __shared__ int cur[16];
  const int b = blockIdx.x;
  const int tid = threadIdx.x;
  if (tid < 16) cur[tid] = Psl[b * 17 + tid];
  __syncthreads();
  const int4* cols4 = (const int4*)(ei + E);
  const int4* rows4 = (const int4*)ei;
  const float4* ew4 = (const float4*)ew;
  const int base = b * EPB;
  for (int t = tid; t < EPB4; t += 256) {
    int4 c = cols4[b * EPB4 + t];
    int4 rr = rows4[b * EPB4 + t];
    float4 w = ew4[b * EPB4 + t];
#pragma unroll
    for (int j = 0; j < 4; ++j) {
      int cc = (j == 0) ? c.x : (j == 1) ? c.y : (j == 2) ? c.z : c.w;
      int rv = (j == 0) ? rr.x : (j == 1) ? rr.y : (j == 2) ? rr.z : rr.w;
      float wv = (j == 0) ? w.x : (j == 1) ? w.y : (j == 2) ? w.z : w.w;
      int r = cc / BINS;
      int pos = base + atomicAdd(&cur[r], 1);
      pe[pos] = make_int2((rv << 13) | (cc - r * BINS), __float_as_int(wv));
    }
  }
}

// ---------------- phase D: per-(range,g) bin histogram over owned slices ----
__global__ __launch_bounds__(256) void k_hist2(const int2* __restrict__ pe, const int* __restrict__ Psl,
                                               int* __restrict__ P) {
  __shared__ int hist[BINS];
  const int r = blockIdx.x / G2;
  const int g = blockIdx.x % G2;
  const int tid = threadIdx.x;
  for (int i = tid; i < BINS; i += 256) hist[i] = 0;
  __syncthreads();
  for (int b = g; b < NPB; b += G2) {
    const int s = Psl[b * 17 + r], e2 = Psl[b * 17 + r + 1];
    const int eb = b * EPB;
    for (int t = s + tid; t < e2; t += 256)
      atomicAdd(&hist[pe[eb + t].x & 0x1FFF], 1);
  }
  __syncthreads();
  for (int i = tid; i < BINS; i += 256) P[(size_t)blockIdx.x * BINS + i] = hist[i];
}

// phase D2: per-bin total -> cnt; P becomes exclusive prefix over g (in place)
__global__ __launch_bounds__(256) void k_reduce(int* __restrict__ P, int* __restrict__ cnt) {
  int b = blockIdx.x * 256 + threadIdx.x;
  if (b >= N) return;
  int r = b / BINS, lb = b % BINS;
  size_t base = (size_t)r * G2 * BINS + lb;
  int run = 0;
#pragma unroll 4
  for (int g = 0; g < G2; ++g) {
    size_t idx = base + (size_t)g * BINS;
    int v = P[idx];
    P[idx] = run;
    run += v;
  }
  cnt[b] = run;
}

__global__ __launch_bounds__(256) void k_bsum(const int* __restrict__ cnt, int* __restrict__ bsum) {
  __shared__ int sh[256];
  int base = blockIdx.x * 1024 + threadIdx.x * 4;
  int s = 0;
  if (base + 3 < N) {
    int4 v = *(const int4*)&cnt[base];
    s = v.x + v.y + v.z + v.w;
  } else {
#pragma unroll
    for (int j = 0; j < 4; ++j)
      if (base + j < N) s += cnt[base + j];
  }
  sh[threadIdx.x] = s;
  __syncthreads();
  for (int o = 128; o > 0; o >>= 1) {
    if (threadIdx.x < o) sh[threadIdx.x] += sh[threadIdx.x + o];
    __syncthreads();
  }
  if (threadIdx.x == 0) bsum[blockIdx.x] = sh[0];
}

__global__ __launch_bounds__(128) void k_bscan(const int* __restrict__ bsum, int* __restrict__ bbase,
                                               int* __restrict__ offN) {
  __shared__ int sh[128];
  const int t = threadIdx.x;
  int v = (t < NB) ? bsum[t] : 0;
  sh[t] = v;
  __syncthreads();
  for (int o = 1; o < 128; o <<= 1) {
    int u = (t >= o) ? sh[t - o] : 0;
    __syncthreads();
    sh[t] += u;
    __syncthreads();
  }
  if (t < NB) bbase[t] = sh[t] - v;
  if (t == 127) *offN = sh[127];
}

__global__ __launch_bounds__(256) void k_off(const int* __restrict__ cnt, const int* __restrict__ bbase,
                                             int* __restrict__ off) {
  __shared__ int sh[256];
  int base = blockIdx.x * 1024 + threadIdx.x * 4;
  int c[4] = {0, 0, 0, 0};
  if (base + 3 < N) {
    int4 v = *(const int4*)&cnt[base];
    c[0] = v.x; c[1] = v.y; c[2] = v.z; c[3] = v.w;
  } else {
#pragma unroll
    for (int j = 0; j < 4; ++j)
      if (base + j < N) c[j] = cnt[base + j];
  }
  int s = c[0] + c[1] + c[2] + c[3];
  sh[threadIdx.x] = s;
  __syncthreads();
  for (int o = 1; o < 256; o <<= 1) {
    int u = (threadIdx.x >= o) ? sh[threadIdx.x - o] : 0;
    __syncthreads();
    sh[threadIdx.x] += u;
    __syncthreads();
  }
  int run = bbase[blockIdx.x] + sh[threadIdx.x] - s;
#pragma unroll
  for (int j = 0; j < 4; ++j) {
    if (base + j < N) { off[base + j] = run; run += c[j]; }
  }
}

// ---------------- phase F: scatter to CSC as packed {row, weight} ----
__global__ __launch_bounds__(256) void k_scatter3(const int2* __restrict__ pe, const int* __restrict__ Psl,
                                                  const int* __restrict__ off, const int* __restrict__ P,
                                                  int2* __restrict__ cpair) {
  __shared__ int base[BINS];
  const int r = blockIdx.x / G2;
  const int g = blockIdx.x % G2;
  const int tid = threadIdx.x;
  for (int i = tid; i < BINS; i += 256)
    base[i] = off[r * BINS + i] + P[(size_t)blockIdx.x * BINS + i];
  __syncthreads();
  for (int b = g; b < NPB; b += G2) {
    const int s = Psl[b * 17 + r], e2 = Psl[b * 17 + r + 1];
    const int eb = b * EPB;
    for (int t = s + tid; t < e2; t += 256) {
      int2 p = pe[eb + t];
      int pos = atomicAdd(&base[p.x & 0x1FFF], 1);
      cpair[pos] = make_int2((int)(((unsigned)p.x) >> 13), p.y);
    }
  }
}

__global__ __launch_bounds__(256) void k_degcsc(const int2* __restrict__ cpair, const int* __restrict__ off,
                                                float* __restrict__ dinv) {
  int i = blockIdx.x * 256 + threadIdx.x;
  if (i >= N) return;
  int b = off[i], e2 = off[i + 1];
  float s = 1.0f;
  for (int p = b; p < e2; ++p) s += __int_as_float(cpair[p].y);
  dinv[i] = rsqrtf(s);
}

// normalize + pack to 4B: (row<<15) | (bf16bits(w) & 0x7FFF)   [w > 0 always]
__global__ __launch_bounds__(256) void k_nrm(const int* __restrict__ off,
                                             const float* __restrict__ dinv,
                                             const int2* __restrict__ cpair,
                                             unsigned* __restrict__ cp4) {
  int i = blockIdx.x * 256 + threadIdx.x;
  if (i >= N) return;
  int b = off[i], e2 = off[i + 1];
  float di = dinv[i];
  for (int p = b; p < e2; ++p) {
    int2 cp = cpair[p];
    float w = dinv[cp.x] * __int_as_float(cp.y) * di;
    unsigned wb = (unsigned)(unsigned short)bf16hi(w);
    cp4[p] = ((unsigned)cp.x << 15) | (wb & 0x7FFFu);
  }
}

// ---- W prep (all 3 mats) + zero BN stats buffers: one dispatch ----
__global__ __launch_bounds__(256) void k_wprep_all(
    const float* __restrict__ W1, const float* __restrict__ W2, const float* __restrict__ Wf1,
    short* __restrict__ wt1h, short* __restrict__ wt1l,
    short* __restrict__ wt2h, short* __restrict__ wt2l,
    short* __restrict__ wtfh, short* __restrict__ wtfl,
    float* __restrict__ st1, float* __restrict__ st2) {
  int idx = blockIdx.x * 256 + threadIdx.x;
  if (idx < 256) st1[idx] = 0.f;
  else if (idx < 512) st2[idx - 256] = 0.f;
  const float* W;
  short *wh, *wl;
  int K, li;
  if (idx < 16384)      { W = W1;  wh = wt1h; wl = wt1l; K = 128; li = idx; }
  else if (idx < 32768) { W = W2;  wh = wt2h; wl = wt2l; K = 128; li = idx - 16384; }
  else if (idx < 81920) { W = Wf1; wh = wtfh; wl = wtfl; K = 384; li = idx - 32768; }
  else return;
  int k = li >> 7, c = li & 127;
  float v = W[(size_t)k * 128 + c];
  short h = bf16hi(v);
  short l = bf16hi(v - bf16f(h));
  wh[(size_t)c * K + k] = h;
  wl[(size_t)c * K + k] = l;
}

// ---- BN params ----
__global__ void k_bnparam(const float* __restrict__ st, const float* __restrict__ gamma,
                          const float* __restrict__ beta, float* __restrict__ p) {
  int t = threadIdx.x;
  if (t >= 128) return;
  const float inv_n = 1.0f / (float)N;
  float m = st[t] * inv_n;
  float var = fmaf(-m, m, st[128 + t] * inv_n);
  float sc = gamma[t] * rsqrtf(var + EPS);
  p[t] = sc;
  p[128 + t] = fmaf(-m, sc, beta[t]);
}

// ---------------- MFMA GEMM with split-bf16 precision ----------------
// OBF16: bf16 output. FC2: fuse final 128->1 dot. AMASK bit s: segment s A is bf16.
template <int KSTEPS, bool OBF16, bool FC2, int AMASK>
__global__ __launch_bounds__(256) void k_gemm_mfma(
    const void* __restrict__ a0, const float* __restrict__ p0,
    const void* __restrict__ a1, const float* __restrict__ p1,
    const void* __restrict__ a2, const float* __restrict__ p2,
    const short* __restrict__ wth, const short* __restrict__ wtl,
    const float* __restrict__ bias, void* __restrict__ Cout,
    const float* __restrict__ wf2, const float* __restrict__ bf2) {
  constexpr int KT = KSTEPS * 32;
  __shared__ short Ah[128][40];
  __shared__ short Al[128][40];
  __shared__ short Bh[128][40];
  __shared__ short Bl[128][40];
  __shared__ float red[2][128];

  const int tid = threadIdx.x;
  const int m0 = blockIdx.x * 128;
  const int sr = tid >> 1;
  const int sk = (tid & 1) * 16;
  const int arow = min(m0 + sr, N - 1);
  const int lane = tid & 63;
  const int lr = lane & 15;
  const int lg = lane >> 4;
  const int wv = tid >> 6;
  const int wr = wv >> 1;
  const int wc = wv & 1;

  f32x4 acc[4][4];
#pragma unroll
  for (int m = 0; m < 4; ++m)
#pragma unroll
    for (int n = 0; n < 4; ++n) acc[m][n] = (f32x4){0.f, 0.f, 0.f, 0.f};

  for (int ks = 0; ks < KSTEPS; ++ks) {
    const int seg = ks >> 2;
    const int koff = (ks & 3) * 32;
    const void* __restrict__ Av = (seg == 0) ? a0 : ((seg == 1) ? a1 : a2);
    const float* __restrict__ P = (seg == 0) ? p0 : ((seg == 1) ? p1 : p2);
    const bool isbf = (AMASK >> seg) & 1;

    float v[16];
    if (isbf) {
      const unsigned short* A16 = (const unsigned short*)Av;
      const uint4* s16 = (const uint4*)&A16[(size_t)arow * F + koff + sk];
      uint4 ua = s16[0], ub = s16[1];
      unsigned uu[8] = {ua.x, ua.y, ua.z, ua.w, ub.x, ub.y, ub.z, ub.w};
#pragma unroll
      for (int j = 0; j < 8; ++j) {
        v[2 * j] = bflo(uu[j]);
        v[2 * j + 1] = bfhi(uu[j]);
      }
    } else {
      const float* A = (const float*)Av;
      const float4* src = (const float4*)(A + (size_t)arow * F + koff + sk);
#pragma unroll
      for (int q = 0; q < 4; ++q) {
        float4 t = src[q];
        v[q * 4 + 0] = t.x; v[q * 4 + 1] = t.y; v[q * 4 + 2] = t.z; v[q * 4 + 3] = t.w;
      }
    }
    if (P) {
      const int c0 = koff + sk;
#pragma unroll
      for (int q = 0; q < 4; ++q) {
        float4 s = *(const float4*)&P[c0 + q * 4];
        float4 b = *(const float4*)&P[128 + c0 + q * 4];
        v[q * 4 + 0] = fmaf(v[q * 4 + 0], s.x, b.x);
        v[q * 4 + 1] = fmaf(v[q * 4 + 1], s.y, b.y);
        v[q * 4 + 2] = fmaf(v[q * 4 + 2], s.z, b.z);
        v[q * 4 + 3] = fmaf(v[q * 4 + 3], s.w, b.w);
      }
    }
    short hh[16], ll[16];
#pragma unroll
    for (int j = 0; j < 16; ++j) {
      hh[j] = bf16hi(v[j]);
      ll[j] = bf16hi(v[j] - bf16f(hh[j]));
    }

    __syncthreads();

    short8 t0, t1, u0, u1;
#pragma unroll
    for (int j = 0; j < 8; ++j) { t0[j] = hh[j]; t1[j] = hh[8 + j]; u0[j] = ll[j]; u1[j] = ll[8 + j]; }
    *(short8*)&Ah[sr][sk] = t0;
    *(short8*)&Ah[sr][sk + 8] = t1;
    *(short8*)&Al[sr][sk] = u0;
    *(short8*)&Al[sr][sk + 8] = u1;

    const size_t wbase = (size_t)sr * KT + ks * 32 + sk;  // global k
    *(short8*)&Bh[sr][sk]     = *(const short8*)&wth[wbase];
    *(short8*)&Bh[sr][sk + 8] = *(const short8*)&wth[wbase + 8];
    *(short8*)&Bl[sr][sk]     = *(const short8*)&wtl[wbase];
    *(short8*)&Bl[sr][sk + 8] = *(const short8*)&wtl[wbase + 8];

    __syncthreads();

    short8 afh[4], afl[4], bfh[4], bfl[4];
#pragma unroll
    for (int m = 0; m < 4; ++m) {
      const int r2 = wr * 64 + m * 16 + lr;
      afh[m] = *(const short8*)&Ah[r2][lg * 8];
      afl[m] = *(const short8*)&Al[r2][lg * 8];
    }
#pragma unroll
    for (int n = 0; n < 4; ++n) {
      const int c2 = wc * 64 + n * 16 + lr;
      bfh[n] = *(const short8*)&Bh[c2][lg * 8];
      bfl[n] = *(const short8*)&Bl[c2][lg * 8];
    }
#pragma unroll
    for (int m = 0; m < 4; ++m)
#pragma unroll
      for (int n = 0; n < 4; ++n) {
        acc[m][n] = __builtin_amdgcn_mfma_f32_16x16x32_bf16(afh[m], bfh[n], acc[m][n], 0, 0, 0);
        acc[m][n] = __builtin_amdgcn_mfma_f32_16x16x32_bf16(afl[m], bfh[n], acc[m][n], 0, 0, 0);
        acc[m][n] = __builtin_amdgcn_mfma_f32_16x16x32_bf16(afh[m], bfl[n], acc[m][n], 0, 0, 0);
      }
  }

  float bv[4];
#pragma unroll
  for (int n = 0; n < 4; ++n) bv[n] = bias ? bias[wc * 64 + n * 16 + lr] : 0.f;

  if (FC2) {
    float w2v[4];
#pragma unroll
    for (int n = 0; n < 4; ++n) w2v[n] = wf2[wc * 64 + n * 16 + lr];
#pragma unroll
    for (int m = 0; m < 4; ++m) {
#pragma unroll
      for (int j = 0; j < 4; ++j) {
        float partial = 0.f;
#pragma unroll
        for (int n = 0; n < 4; ++n)
          partial += fmaxf(acc[m][n][j] + bv[n], 0.f) * w2v[n];
#pragma unroll
        for (int o = 8; o >= 1; o >>= 1) partial += __shfl_xor(partial, o, 16);
        if (lr == 0) red[wc][wr * 64 + m * 16 + lg * 4 + j] = partial;
      }
    }
    __syncthreads();
    if (tid < 128) {
      const int row = m0 + tid;
      if (row < N) {
        float s = red[0][tid] + red[1][tid] + bf2[0];
        ((float*)Cout)[row] = fmaxf(s, 0.f);
      }
    }
  } else {
#pragma unroll
    for (int m = 0; m < 4; ++m) {
#pragma unroll
      for (int j = 0; j < 4; ++j) {
        const int row = m0 + wr * 64 + m * 16 + lg * 4 + j;
        if (row < N) {
#pragma unroll
          for (int n = 0; n < 4; ++n) {
            const int col = wc * 64 + n * 16 + lr;
            float o = acc[m][n][j] + bv[n];
            if (bias) o = fmaxf(o, 0.f);
            if (OBF16) {
              ((unsigned short*)Cout)[(size_t)row * F + col] = (unsigned short)bf16hi(o);
            } else {
              ((float*)Cout)[(size_t)row * F + col] = o;
            }
          }
        }
      }
    }
  }
}

// ---------------- aggregation: 1 wave/node, 4B(2xbf16)/lane, 8 gathers in flight;
// 4B packed CSC entries; packed bf16 output  [R8/R13 measured-best shape] ----------------
__global__ __launch_bounds__(256) void k_agg(
    const unsigned* __restrict__ h,  // bf16 pairs: h[i*64+lane] = cols {2lane, 2lane+1}
    const unsigned* __restrict__ cp4, const int* __restrict__ off,
    const float* __restrict__ dinv, const float* __restrict__ bias,
    unsigned* __restrict__ out) {
  const int i = blockIdx.x * 4 + (threadIdx.x >> 6);
  if (i >= N) return;
  const int lane = threadIdx.x & 63;
  const float di = dinv[i];
  unsigned sv = h[(size_t)i * 64 + lane];
  float acc0 = di * di * bflo(sv);
  float acc1 = di * di * bfhi(sv);
  int e = off[i];
  const int eend = off[i + 1];
  for (; e + 8 <= eend; e += 8) {
    unsigned u[8];
    unsigned vv[8];
#pragma unroll
    for (int j = 0; j < 8; ++j) u[j] = cp4[e + j];
#pragma unroll
    for (int j = 0; j < 8; ++j) vv[j] = h[(size_t)(u[j] >> 15) * 64 + lane];
#pragma unroll
    for (int j = 0; j < 8; ++j) {
      float w = __uint_as_float((u[j] & 0x7FFFu) << 16);
      acc0 = fmaf(w, bflo(vv[j]), acc0);
      acc1 = fmaf(w, bfhi(vv[j]), acc1);
    }
  }
  for (; e < eend; ++e) {
    unsigned u = cp4[e];
    float w = __uint_as_float((u & 0x7FFFu) << 16);
    unsigned v = h[(size_t)(u >> 15) * 64 + lane];
    acc0 = fmaf(w, bflo(v), acc0);
    acc1 = fmaf(w, bfhi(v), acc1);
  }
  float2 b = *(const float2*)&bias[lane * 2];
  float o0 = fmaxf(acc0 + b.x, 0.f);
  float o1 = fmaxf(acc1 + b.y, 0.f);
  unsigned pack = ((unsigned)(unsigned short)bf16hi(o0)) |
                  (((unsigned)(unsigned short)bf16hi(o1)) << 16);
  out[(size_t)i * 64 + lane] = pack;
}

// ---------------- BN stats over packed-bf16 h ----------------
__global__ __launch_bounds__(256) void k_stats(const unsigned* __restrict__ h2, float* __restrict__ sums) {
  const int cp = threadIdx.x & 63;   // column pair {2cp, 2cp+1}
  const int q = threadIdx.x >> 6;    // row quarter
  float s0 = 0.f, s1 = 0.f, q0 = 0.f, q1 = 0.f;
  for (int r = blockIdx.x * 4 + q; r < N; r += gridDim.x * 4) {
    unsigned u = h2[(size_t)r * 64 + cp];
    float lo = bflo(u), hi = bfhi(u);
    s0 += lo; s1 += hi;
    q0 = fmaf(lo, lo, q0);
    q1 = fmaf(hi, hi, q1);
  }
  __shared__ float2 sh[256];
  sh[threadIdx.x] = make_float2(s0, s1);
  __syncthreads();
  if (q == 0) {
    float2 a = sh[cp], b = sh[64 + cp], c = sh[128 + cp], d = sh[192 + cp];
    atomicAdd(&sums[2 * cp], a.x + b.x + c.x + d.x);
    atomicAdd(&sums[2 * cp + 1], a.y + b.y + c.y + d.y);
  }
  __syncthreads();
  sh[threadIdx.x] = make_float2(q0, q1);
  __syncthreads();
  if (q == 0) {
    float2 a = sh[cp], b = sh[64 + cp], c = sh[128 + cp], d = sh[192 + cp];
    atomicAdd(&sums[128 + 2 * cp], a.x + b.x + c.x + d.x);
    atomicAdd(&sums[128 + 2 * cp + 1], a.y + b.y + c.y + d.y);
  }
}

extern "C" void kernel_launch(void* const* d_in, const int* in_sizes, int n_in,
                              void* d_out, int out_size, void* d_ws, size_t ws_size,
                              hipStream_t stream) {
  const float* x   = (const float*)d_in[0];
  const int*   ei  = (const int*)d_in[1];
  const float* ew  = (const float*)d_in[2];
  const float* W1  = (const float*)d_in[3];
  const float* b1  = (const float*)d_in[4];
  const float* W2  = (const float*)d_in[5];
  const float* b2  = (const float*)d_in[6];
  const float* g1  = (const float*)d_in[7];
  const float* be1 = (const float*)d_in[8];
  const float* g2  = (const float*)d_in[9];
  const float* be2 = (const float*)d_in[10];
  const float* Wf1 = (const float*)d_in[11];
  const float* bf1 = (const float*)d_in[12];
  const float* Wf2 = (const float*)d_in[13];
  const float* bf2 = (const float*)d_in[14];
  float* out = (float*)d_out;

  char* p = (char*)d_ws;
  auto take = [&](size_t bytes) {
    char* r = p;
    p += (bytes + 255) & ~(size_t)255;
    return r;
  };
  float* st1  = (float*)take(256 * 4);
  float* st2  = (float*)take(256 * 4);
  int*   cnt  = (int*)take((size_t)N * 4);
  int*   off  = (int*)take((size_t)(N + 1) * 4);
  int*   bsum = (int*)take((size_t)NB * 4);
  int*   bbase= (int*)take((size_t)NB * 4);
  int*   Psl  = (int*)take((size_t)NPB * 17 * 4);
  int2*  pe   = (int2*)take((size_t)E * 8);
  int*   Phist= (int*)take((size_t)R_RNG * G2 * BINS * 4);
  float* dinv = (float*)take((size_t)N * 4);
  float* p1   = (float*)take(256 * 4);
  float* p2   = (float*)take(256 * 4);
  short* wt1h = (short*)take((size_t)128 * 128 * 2);
  short* wt1l = (short*)take((size_t)128 * 128 * 2);
  short* wt2h = (short*)take((size_t)128 * 128 * 2);
  short* wt2l = (short*)take((size_t)128 * 128 * 2);
  short* wtfh = (short*)take((size_t)128 * 384 * 2);
  short* wtfl = (short*)take((size_t)128 * 384 * 2);
  int2*  cpair= (int2*)take((size_t)E * 8);
  unsigned* cp4 = (unsigned*)take((size_t)E * 4);
  unsigned short* bufH  = (unsigned short*)take((size_t)N * F * 2);  // conv out (gathered)
  unsigned short* bufB16= (unsigned short*)take((size_t)N * F * 2);  // h1 bf16
  unsigned short* bufC16= (unsigned short*)take((size_t)N * F * 2);  // h2 bf16

  // W prep + BN-stats zeroing
  k_wprep_all<<<320, 256, 0, stream>>>(W1, W2, Wf1, wt1h, wt1l, wt2h, wt2l, wtfh, wtfl, st1, st2);

  // partition-based atomic-free CSC build
  k_phist<<<NPB, 256, 0, stream>>>(ei, Psl);
  k_pscatter<<<NPB, 256, 0, stream>>>(ei, ew, Psl, pe);
  k_hist2<<<R_RNG * G2, 256, 0, stream>>>(pe, Psl, Phist);
  k_reduce<<<(N + 255) / 256, 256, 0, stream>>>(Phist, cnt);
  k_bsum<<<NB, 256, 0, stream>>>(cnt, bsum);
  k_bscan<<<1, 128, 0, stream>>>(bsum, bbase, &off[N]);
  k_off<<<NB, 256, 0, stream>>>(cnt, bbase, off);
  k_scatter3<<<R_RNG * G2, 256, 0, stream>>>(pe, Psl, off, Phist, cpair);
  k_degcsc<<<(N + 255) / 256, 256, 0, stream>>>(cpair, off, dinv);
  k_nrm<<<(N + 255) / 256, 256, 0, stream>>>(off, dinv, cpair, cp4);

  const int gemm_grid = (N + 127) / 128;
  // conv1: bufH(bf16) = x @ W1
  k_gemm_mfma<4, true, false, 0><<<gemm_grid, 256, 0, stream>>>(
      x, nullptr, nullptr, nullptr, nullptr, nullptr, wt1h, wt1l, nullptr, bufH, nullptr, nullptr);
  k_agg<<<(N + 3) / 4, 256, 0, stream>>>((const unsigned*)bufH, cp4, off, dinv, b1,
                                         (unsigned*)bufB16);
  k_stats<<<256, 256, 0, stream>>>((const unsigned*)bufB16, st1);
  k_bnparam<<<1, 128, 0, stream>>>(st1, g1, be1, p1);
  // conv2: bufH(bf16) = bn1(h1_bf16) @ W2   (A is bf16)
  k_gemm_mfma<4, true, false, 1><<<gemm_grid, 256, 0, stream>>>(
      bufB16, p1, nullptr, nullptr, nullptr, nullptr, wt2h, wt2l, nullptr, bufH, nullptr, nullptr);
  k_agg<<<(N + 3) / 4, 256, 0, stream>>>((const unsigned*)bufH, cp4, off, dinv, b2,
                                         (unsigned*)bufC16);
  k_stats<<<256, 256, 0, stream>>>((const unsigned*)bufC16, st2);
  k_bnparam<<<1, 128, 0, stream>>>(st2, g2, be2, p2);
  // fc1 + fused fc2 over [x | bn1(h1) | bn2(h2)] -> out[N]  (segs 1,2 bf16)
  k_gemm_mfma<12, false, true, 6><<<gemm_grid, 256, 0, stream>>>(
      x, nullptr, bufB16, p1, bufC16, p2, wtfh, wtfl, bf1, out, Wf2, bf2);
}

// Round 16
// 427.746 us; speedup vs baseline: 1.2399x; 1.0155x over previous
//
#include <hip/hip_runtime.h>

typedef __attribute__((ext_vector_type(8))) short short8;
typedef __attribute__((ext_vector_type(4))) float f32x4;

constexpr int N = 100000;
constexpr int E = 1600000;
constexpr int F = 128;
constexpr float EPS = 1e-5f;
constexpr int NB = (N + 1023) / 1024;  // 98 scan blocks

// partitioned counting-sort geometry
constexpr int R_RNG = 16;
constexpr int BINS = 6250;           // R_RNG*BINS == N exactly
constexpr int G2 = 32;               // blocks per range in hist2/scatter3 (R15: 64)
constexpr int NPB = 640;             // partition blocks
constexpr int EPB = E / NPB;         // 2500 edges per partition block
constexpr int EPB4 = EPB / 4;        // 625 int4 per partition block

// ---- bf16 split helpers (RNE) ----
__device__ __forceinline__ short bf16hi(float v) {
  unsigned u = __float_as_uint(v);
  unsigned r = (u + 0x7fffu + ((u >> 16) & 1u)) >> 16;
  return (short)r;
}
__device__ __forceinline__ float bf16f(short h) {
  return __uint_as_float(((unsigned)(unsigned short)h) << 16);
}
__device__ __forceinline__ float bflo(unsigned v) {
  return __uint_as_float(v << 16);
}
__device__ __forceinline__ float bfhi(unsigned v) {
  return __uint_as_float(v & 0xffff0000u);
}

// ---------------- phase A: per-block 16-range histogram + block-local prefix ----
__global__ __launch_bounds__(256) void k_phist(const int* __restrict__ ei, int* __restrict__ Psl) {
  __shared__ int h16[16];
  const int b = blockIdx.x;
  const int tid = threadIdx.x;
  if (tid < 16) h16[tid] = 0;
  __syncthreads();
  const int4* cols4 = (const int4*)(ei + E);
  for (int t = tid; t < EPB4; t += 256) {
    int4 c = cols4[b * EPB4 + t];
    atomicAdd(&h16[c.x / BINS], 1);
    atomicAdd(&h16[c.y / BINS], 1);
    atomicAdd(&h16[c.z / BINS], 1);
    atomicAdd(&h16[c.w / BINS], 1);
  }
  __syncthreads();
  if (tid == 0) {
    int run = 0;
#pragma unroll
    for (int r = 0; r < 16; ++r) { Psl[b * 17 + r] = run; run += h16[r]; }
    Psl[b * 17 + 16] = run;  // == EPB
  }
}

// ---------------- phase C: partition edges into per-(block,range) slices ----
__global__ __launch_bounds__(256) void k_pscatter(const int* __restrict__ ei, const float* __restrict__ ew,
                                                  const int* __restrict__ Psl, int2* __restrict__ pe) {
  __shared__ int cur[16];
  const int b = blockIdx.x;
  const int tid = threadIdx.x;
  if (tid < 16) cur[tid] = Psl[b * 17 + tid];
  __syncthreads();
  const int4* cols4 = (const int4*)(ei + E);
  const int4* rows4 = (const int4*)ei;
  const float4* ew4 = (const float4*)ew;
  const int base = b * EPB;
  for (int t = tid; t < EPB4; t += 256) {
    int4 c = cols4[b * EPB4 + t];
    int4 rr = rows4[b * EPB4 + t];
    float4 w = ew4[b * EPB4 + t];
#pragma unroll
    for (int j = 0; j < 4; ++j) {
      int cc = (j == 0) ? c.x : (j == 1) ? c.y : (j == 2) ? c.z : c.w;
      int rv = (j == 0) ? rr.x : (j == 1) ? rr.y : (j == 2) ? rr.z : rr.w;
      float wv = (j == 0) ? w.x : (j == 1) ? w.y : (j == 2) ? w.z : w.w;
      int r = cc / BINS;
      int pos = base + atomicAdd(&cur[r], 1);
      pe[pos] = make_int2((rv << 13) | (cc - r * BINS), __float_as_int(wv));
    }
  }
}

// ---------------- phase D: per-(range,g) bin histogram over owned slices ----
__global__ __launch_bounds__(256) void k_hist2(const int2* __restrict__ pe, const int* __restrict__ Psl,
                                               int* __restrict__ P) {
  __shared__ int hist[BINS];
  const int r = blockIdx.x / G2;
  const int g = blockIdx.x % G2;
  const int tid = threadIdx.x;
  for (int i = tid; i < BINS; i += 256) hist[i] = 0;
  __syncthreads();
  for (int b = g; b < NPB; b += G2) {
    const int s = Psl[b * 17 + r], e2 = Psl[b * 17 + r + 1];
    const int eb = b * EPB;
    for (int t = s + tid; t < e2; t += 256)
      atomicAdd(&hist[pe[eb + t].x & 0x1FFF], 1);
  }
  __syncthreads();
  for (int i = tid; i < BINS; i += 256) P[(size_t)blockIdx.x * BINS + i] = hist[i];
}

// phase D2: per-bin total -> cnt; P becomes exclusive prefix over g (in place)
__global__ __launch_bounds__(256) void k_reduce(int* __restrict__ P, int* __restrict__ cnt) {
  int b = blockIdx.x * 256 + threadIdx.x;
  if (b >= N) return;
  int r = b / BINS, lb = b % BINS;
  size_t base = (size_t)r * G2 * BINS + lb;
  int run = 0;
#pragma unroll 4
  for (int g = 0; g < G2; ++g) {
    size_t idx = base + (size_t)g * BINS;
    int v = P[idx];
    P[idx] = run;
    run += v;
  }
  cnt[b] = run;
}

__global__ __launch_bounds__(256) void k_bsum(const int* __restrict__ cnt, int* __restrict__ bsum) {
  __shared__ int sh[256];
  int base = blockIdx.x * 1024 + threadIdx.x * 4;
  int s = 0;
  if (base + 3 < N) {
    int4 v = *(const int4*)&cnt[base];
    s = v.x + v.y + v.z + v.w;
  } else {
#pragma unroll
    for (int j = 0; j < 4; ++j)
      if (base + j < N) s += cnt[base + j];
  }
  sh[threadIdx.x] = s;
  __syncthreads();
  for (int o = 128; o > 0; o >>= 1) {
    if (threadIdx.x < o) sh[threadIdx.x] += sh[threadIdx.x + o];
    __syncthreads();
  }
  if (threadIdx.x == 0) bsum[blockIdx.x] = sh[0];
}

__global__ __launch_bounds__(128) void k_bscan(const int* __restrict__ bsum, int* __restrict__ bbase,
                                               int* __restrict__ offN) {
  __shared__ int sh[128];
  const int t = threadIdx.x;
  int v = (t < NB) ? bsum[t] : 0;
  sh[t] = v;
  __syncthreads();
  for (int o = 1; o < 128; o <<= 1) {
    int u = (t >= o) ? sh[t - o] : 0;
    __syncthreads();
    sh[t] += u;
    __syncthreads();
  }
  if (t < NB) bbase[t] = sh[t] - v;
  if (t == 127) *offN = sh[127];
}

__global__ __launch_bounds__(256) void k_off(const int* __restrict__ cnt, const int* __restrict__ bbase,
                                             int* __restrict__ off) {
  __shared__ int sh[256];
  int base = blockIdx.x * 1024 + threadIdx.x * 4;
  int c[4] = {0, 0, 0, 0};
  if (base + 3 < N) {
    int4 v = *(const int4*)&cnt[base];
    c[0] = v.x; c[1] = v.y; c[2] = v.z; c[3] = v.w;
  } else {
#pragma unroll
    for (int j = 0; j < 4; ++j)
      if (base + j < N) c[j] = cnt[base + j];
  }
  int s = c[0] + c[1] + c[2] + c[3];
  sh[threadIdx.x] = s;
  __syncthreads();
  for (int o = 1; o < 256; o <<= 1) {
    int u = (threadIdx.x >= o) ? sh[threadIdx.x - o] : 0;
    __syncthreads();
    sh[threadIdx.x] += u;
    __syncthreads();
  }
  int run = bbase[blockIdx.x] + sh[threadIdx.x] - s;
#pragma unroll
  for (int j = 0; j < 4; ++j) {
    if (base + j < N) { off[base + j] = run; run += c[j]; }
  }
}

// ---------------- phase F: scatter to CSC as packed {row, weight} ----
__global__ __launch_bounds__(256) void k_scatter3(const int2* __restrict__ pe, const int* __restrict__ Psl,
                                                  const int* __restrict__ off, const int* __restrict__ P,
                                                  int2* __restrict__ cpair) {
  __shared__ int base[BINS];
  const int r = blockIdx.x / G2;
  const int g = blockIdx.x % G2;
  const int tid = threadIdx.x;
  for (int i = tid; i < BINS; i += 256)
    base[i] = off[r * BINS + i] + P[(size_t)blockIdx.x * BINS + i];
  __syncthreads();
  for (int b = g; b < NPB; b += G2) {
    const int s = Psl[b * 17 + r], e2 = Psl[b * 17 + r + 1];
    const int eb = b * EPB;
    for (int t = s + tid; t < e2; t += 256) {
      int2 p = pe[eb + t];
      int pos = atomicAdd(&base[p.x & 0x1FFF], 1);
      cpair[pos] = make_int2((int)(((unsigned)p.x) >> 13), p.y);
    }
  }
}

__global__ __launch_bounds__(256) void k_degcsc(const int2* __restrict__ cpair, const int* __restrict__ off,
                                                float* __restrict__ dinv) {
  int i = blockIdx.x * 256 + threadIdx.x;
  if (i >= N) return;
  int b = off[i], e2 = off[i + 1];
  float s = 1.0f;
  for (int p = b; p < e2; ++p) s += __int_as_float(cpair[p].y);
  dinv[i] = rsqrtf(s);
}

// normalize + pack to 4B: (row<<15) | (bf16bits(w) & 0x7FFF)   [w > 0 always]
__global__ __launch_bounds__(256) void k_nrm(const int* __restrict__ off,
                                             const float* __restrict__ dinv,
                                             const int2* __restrict__ cpair,
                                             unsigned* __restrict__ cp4) {
  int i = blockIdx.x * 256 + threadIdx.x;
  if (i >= N) return;
  int b = off[i], e2 = off[i + 1];
  float di = dinv[i];
  for (int p = b; p < e2; ++p) {
    int2 cp = cpair[p];
    float w = dinv[cp.x] * __int_as_float(cp.y) * di;
    unsigned wb = (unsigned)(unsigned short)bf16hi(w);
    cp4[p] = ((unsigned)cp.x << 15) | (wb & 0x7FFFu);
  }
}

// ---- W prep (all 3 mats) + zero BN stats buffers: one dispatch ----
__global__ __launch_bounds__(256) void k_wprep_all(
    const float* __restrict__ W1, const float* __restrict__ W2, const float* __restrict__ Wf1,
    short* __restrict__ wt1h, short* __restrict__ wt1l,
    short* __restrict__ wt2h, short* __restrict__ wt2l,
    short* __restrict__ wtfh, short* __restrict__ wtfl,
    float* __restrict__ st1, float* __restrict__ st2) {
  int idx = blockIdx.x * 256 + threadIdx.x;
  if (idx < 256) st1[idx] = 0.f;
  else if (idx < 512) st2[idx - 256] = 0.f;
  const float* W;
  short *wh, *wl;
  int K, li;
  if (idx < 16384)      { W = W1;  wh = wt1h; wl = wt1l; K = 128; li = idx; }
  else if (idx < 32768) { W = W2;  wh = wt2h; wl = wt2l; K = 128; li = idx - 16384; }
  else if (idx < 81920) { W = Wf1; wh = wtfh; wl = wtfl; K = 384; li = idx - 32768; }
  else return;
  int k = li >> 7, c = li & 127;
  float v = W[(size_t)k * 128 + c];
  short h = bf16hi(v);
  short l = bf16hi(v - bf16f(h));
  wh[(size_t)c * K + k] = h;
  wl[(size_t)c * K + k] = l;
}

// ---- BN params ----
__global__ void k_bnparam(const float* __restrict__ st, const float* __restrict__ gamma,
                          const float* __restrict__ beta, float* __restrict__ p) {
  int t = threadIdx.x;
  if (t >= 128) return;
  const float inv_n = 1.0f / (float)N;
  float m = st[t] * inv_n;
  float var = fmaf(-m, m, st[128 + t] * inv_n);
  float sc = gamma[t] * rsqrtf(var + EPS);
  p[t] = sc;
  p[128 + t] = fmaf(-m, sc, beta[t]);
}

// ---------------- MFMA GEMM with split-bf16 precision ----------------
// OBF16: bf16 output. FC2: fuse final 128->1 dot. AMASK bit s: segment s A is bf16.
template <int KSTEPS, bool OBF16, bool FC2, int AMASK>
__global__ __launch_bounds__(256) void k_gemm_mfma(
    const void* __restrict__ a0, const float* __restrict__ p0,
    const void* __restrict__ a1, const float* __restrict__ p1,
    const void* __restrict__ a2, const float* __restrict__ p2,
    const short* __restrict__ wth, const short* __restrict__ wtl,
    const float* __restrict__ bias, void* __restrict__ Cout,
    const float* __restrict__ wf2, const float* __restrict__ bf2) {
  constexpr int KT = KSTEPS * 32;
  __shared__ short Ah[128][40];
  __shared__ short Al[128][40];
  __shared__ short Bh[128][40];
  __shared__ short Bl[128][40];
  __shared__ float red[2][128];

  const int tid = threadIdx.x;
  const int m0 = blockIdx.x * 128;
  const int sr = tid >> 1;
  const int sk = (tid & 1) * 16;
  const int arow = min(m0 + sr, N - 1);
  const int lane = tid & 63;
  const int lr = lane & 15;
  const int lg = lane >> 4;
  const int wv = tid >> 6;
  const int wr = wv >> 1;
  const int wc = wv & 1;

  f32x4 acc[4][4];
#pragma unroll
  for (int m = 0; m < 4; ++m)
#pragma unroll
    for (int n = 0; n < 4; ++n) acc[m][n] = (f32x4){0.f, 0.f, 0.f, 0.f};

  for (int ks = 0; ks < KSTEPS; ++ks) {
    const int seg = ks >> 2;
    const int koff = (ks & 3) * 32;
    const void* __restrict__ Av = (seg == 0) ? a0 : ((seg == 1) ? a1 : a2);
    const float* __restrict__ P = (seg == 0) ? p0 : ((seg == 1) ? p1 : p2);
    const bool isbf = (AMASK >> seg) & 1;

    float v[16];
    if (isbf) {
      const unsigned short* A16 = (const unsigned short*)Av;
      const uint4* s16 = (const uint4*)&A16[(size_t)arow * F + koff + sk];
      uint4 ua = s16[0], ub = s16[1];
      unsigned uu[8] = {ua.x, ua.y, ua.z, ua.w, ub.x, ub.y, ub.z, ub.w};
#pragma unroll
      for (int j = 0; j < 8; ++j) {
        v[2 * j] = bflo(uu[j]);
        v[2 * j + 1] = bfhi(uu[j]);
      }
    } else {
      const float* A = (const float*)Av;
      const float4* src = (const float4*)(A + (size_t)arow * F + koff + sk);
#pragma unroll
      for (int q = 0; q < 4; ++q) {
        float4 t = src[q];
        v[q * 4 + 0] = t.x; v[q * 4 + 1] = t.y; v[q * 4 + 2] = t.z; v[q * 4 + 3] = t.w;
      }
    }
    if (P) {
      const int c0 = koff + sk;
#pragma unroll
      for (int q = 0; q < 4; ++q) {
        float4 s = *(const float4*)&P[c0 + q * 4];
        float4 b = *(const float4*)&P[128 + c0 + q * 4];
        v[q * 4 + 0] = fmaf(v[q * 4 + 0], s.x, b.x);
        v[q * 4 + 1] = fmaf(v[q * 4 + 1], s.y, b.y);
        v[q * 4 + 2] = fmaf(v[q * 4 + 2], s.z, b.z);
        v[q * 4 + 3] = fmaf(v[q * 4 + 3], s.w, b.w);
      }
    }
    short hh[16], ll[16];
#pragma unroll
    for (int j = 0; j < 16; ++j) {
      hh[j] = bf16hi(v[j]);
      ll[j] = bf16hi(v[j] - bf16f(hh[j]));
    }

    __syncthreads();

    short8 t0, t1, u0, u1;
#pragma unroll
    for (int j = 0; j < 8; ++j) { t0[j] = hh[j]; t1[j] = hh[8 + j]; u0[j] = ll[j]; u1[j] = ll[8 + j]; }
    *(short8*)&Ah[sr][sk] = t0;
    *(short8*)&Ah[sr][sk + 8] = t1;
    *(short8*)&Al[sr][sk] = u0;
    *(short8*)&Al[sr][sk + 8] = u1;

    const size_t wbase = (size_t)sr * KT + ks * 32 + sk;  // global k
    *(short8*)&Bh[sr][sk]     = *(const short8*)&wth[wbase];
    *(short8*)&Bh[sr][sk + 8] = *(const short8*)&wth[wbase + 8];
    *(short8*)&Bl[sr][sk]     = *(const short8*)&wtl[wbase];
    *(short8*)&Bl[sr][sk + 8] = *(const short8*)&wtl[wbase + 8];

    __syncthreads();

    short8 afh[4], afl[4], bfh[4], bfl[4];
#pragma unroll
    for (int m = 0; m < 4; ++m) {
      const int r2 = wr * 64 + m * 16 + lr;
      afh[m] = *(const short8*)&Ah[r2][lg * 8];
      afl[m] = *(const short8*)&Al[r2][lg * 8];
    }
#pragma unroll
    for (int n = 0; n < 4; ++n) {
      const int c2 = wc * 64 + n * 16 + lr;
      bfh[n] = *(const short8*)&Bh[c2][lg * 8];
      bfl[n] = *(const short8*)&Bl[c2][lg * 8];
    }
#pragma unroll
    for (int m = 0; m < 4; ++m)
#pragma unroll
      for (int n = 0; n < 4; ++n) {
        acc[m][n] = __builtin_amdgcn_mfma_f32_16x16x32_bf16(afh[m], bfh[n], acc[m][n], 0, 0, 0);
        acc[m][n] = __builtin_amdgcn_mfma_f32_16x16x32_bf16(afl[m], bfh[n], acc[m][n], 0, 0, 0);
        acc[m][n] = __builtin_amdgcn_mfma_f32_16x16x32_bf16(afh[m], bfl[n], acc[m][n], 0, 0, 0);
      }
  }

  float bv[4];
#pragma unroll
  for (int n = 0; n < 4; ++n) bv[n] = bias ? bias[wc * 64 + n * 16 + lr] : 0.f;

  if (FC2) {
    float w2v[4];
#pragma unroll
    for (int n = 0; n < 4; ++n) w2v[n] = wf2[wc * 64 + n * 16 + lr];
#pragma unroll
    for (int m = 0; m < 4; ++m) {
#pragma unroll
      for (int j = 0; j < 4; ++j) {
        float partial = 0.f;
#pragma unroll
        for (int n = 0; n < 4; ++n)
          partial += fmaxf(acc[m][n][j] + bv[n], 0.f) * w2v[n];
#pragma unroll
        for (int o = 8; o >= 1; o >>= 1) partial += __shfl_xor(partial, o, 16);
        if (lr == 0) red[wc][wr * 64 + m * 16 + lg * 4 + j] = partial;
      }
    }
    __syncthreads();
    if (tid < 128) {
      const int row = m0 + tid;
      if (row < N) {
        float s = red[0][tid] + red[1][tid] + bf2[0];
        ((float*)Cout)[row] = fmaxf(s, 0.f);
      }
    }
  } else {
#pragma unroll
    for (int m = 0; m < 4; ++m) {
#pragma unroll
      for (int j = 0; j < 4; ++j) {
        const int row = m0 + wr * 64 + m * 16 + lg * 4 + j;
        if (row < N) {
#pragma unroll
          for (int n = 0; n < 4; ++n) {
            const int col = wc * 64 + n * 16 + lr;
            float o = acc[m][n][j] + bv[n];
            if (bias) o = fmaxf(o, 0.f);
            if (OBF16) {
              ((unsigned short*)Cout)[(size_t)row * F + col] = (unsigned short)bf16hi(o);
            } else {
              ((float*)Cout)[(size_t)row * F + col] = o;
            }
          }
        }
      }
    }
  }
}

// ---------------- aggregation: 1 wave/node, 4B(2xbf16)/lane, 8 gathers in flight;
// 4B packed CSC entries; packed bf16 output  [R15 measured-best — DO NOT TOUCH] ----------------
__global__ __launch_bounds__(256) void k_agg(
    const unsigned* __restrict__ h,  // bf16 pairs: h[i*64+lane] = cols {2lane, 2lane+1}
    const unsigned* __restrict__ cp4, const int* __restrict__ off,
    const float* __restrict__ dinv, const float* __restrict__ bias,
    unsigned* __restrict__ out) {
  const int i = blockIdx.x * 4 + (threadIdx.x >> 6);
  if (i >= N) return;
  const int lane = threadIdx.x & 63;
  const float di = dinv[i];
  unsigned sv = h[(size_t)i * 64 + lane];
  float acc0 = di * di * bflo(sv);
  float acc1 = di * di * bfhi(sv);
  int e = off[i];
  const int eend = off[i + 1];
  for (; e + 8 <= eend; e += 8) {
    unsigned u[8];
    unsigned vv[8];
#pragma unroll
    for (int j = 0; j < 8; ++j) u[j] = cp4[e + j];
#pragma unroll
    for (int j = 0; j < 8; ++j) vv[j] = h[(size_t)(u[j] >> 15) * 64 + lane];
#pragma unroll
    for (int j = 0; j < 8; ++j) {
      float w = __uint_as_float((u[j] & 0x7FFFu) << 16);
      acc0 = fmaf(w, bflo(vv[j]), acc0);
      acc1 = fmaf(w, bfhi(vv[j]), acc1);
    }
  }
  for (; e < eend; ++e) {
    unsigned u = cp4[e];
    float w = __uint_as_float((u & 0x7FFFu) << 16);
    unsigned v = h[(size_t)(u >> 15) * 64 + lane];
    acc0 = fmaf(w, bflo(v), acc0);
    acc1 = fmaf(w, bfhi(v), acc1);
  }
  float2 b = *(const float2*)&bias[lane * 2];
  float o0 = fmaxf(acc0 + b.x, 0.f);
  float o1 = fmaxf(acc1 + b.y, 0.f);
  unsigned pack = ((unsigned)(unsigned short)bf16hi(o0)) |
                  (((unsigned)(unsigned short)bf16hi(o1)) << 16);
  out[(size_t)i * 64 + lane] = pack;
}

// ---------------- BN stats over packed-bf16 h ----------------
__global__ __launch_bounds__(256) void k_stats(const unsigned* __restrict__ h2, float* __restrict__ sums) {
  const int cp = threadIdx.x & 63;   // column pair {2cp, 2cp+1}
  const int q = threadIdx.x >> 6;    // row quarter
  float s0 = 0.f, s1 = 0.f, q0 = 0.f, q1 = 0.f;
  for (int r = blockIdx.x * 4 + q; r < N; r += gridDim.x * 4) {
    unsigned u = h2[(size_t)r * 64 + cp];
    float lo = bflo(u), hi = bfhi(u);
    s0 += lo; s1 += hi;
    q0 = fmaf(lo, lo, q0);
    q1 = fmaf(hi, hi, q1);
  }
  __shared__ float2 sh[256];
  sh[threadIdx.x] = make_float2(s0, s1);
  __syncthreads();
  if (q == 0) {
    float2 a = sh[cp], b = sh[64 + cp], c = sh[128 + cp], d = sh[192 + cp];
    atomicAdd(&sums[2 * cp], a.x + b.x + c.x + d.x);
    atomicAdd(&sums[2 * cp + 1], a.y + b.y + c.y + d.y);
  }
  __syncthreads();
  sh[threadIdx.x] = make_float2(q0, q1);
  __syncthreads();
  if (q == 0) {
    float2 a = sh[cp], b = sh[64 + cp], c = sh[128 + cp], d = sh[192 + cp];
    atomicAdd(&sums[128 + 2 * cp], a.x + b.x + c.x + d.x);
    atomicAdd(&sums[128 + 2 * cp + 1], a.y + b.y + c.y + d.y);
  }
}

extern "C" void kernel_launch(void* const* d_in, const int* in_sizes, int n_in,
                              void* d_out, int out_size, void* d_ws, size_t ws_size,
                              hipStream_t stream) {
  const float* x   = (const float*)d_in[0];
  const int*   ei  = (const int*)d_in[1];
  const float* ew  = (const float*)d_in[2];
  const float* W1  = (const float*)d_in[3];
  const float* b1  = (const float*)d_in[4];
  const float* W2  = (const float*)d_in[5];
  const float* b2  = (const float*)d_in[6];
  const float* g1  = (const float*)d_in[7];
  const float* be1 = (const float*)d_in[8];
  const float* g2  = (const float*)d_in[9];
  const float* be2 = (const float*)d_in[10];
  const float* Wf1 = (const float*)d_in[11];
  const float* bf1 = (const float*)d_in[12];
  const float* Wf2 = (const float*)d_in[13];
  const float* bf2 = (const float*)d_in[14];
  float* out = (float*)d_out;

  char* p = (char*)d_ws;
  auto take = [&](size_t bytes) {
    char* r = p;
    p += (bytes + 255) & ~(size_t)255;
    return r;
  };
  float* st1  = (float*)take(256 * 4);
  float* st2  = (float*)take(256 * 4);
  int*   cnt  = (int*)take((size_t)N * 4);
  int*   off  = (int*)take((size_t)(N + 1) * 4);
  int*   bsum = (int*)take((size_t)NB * 4);
  int*   bbase= (int*)take((size_t)NB * 4);
  int*   Psl  = (int*)take((size_t)NPB * 17 * 4);
  int2*  pe   = (int2*)take((size_t)E * 8);
  int*   Phist= (int*)take((size_t)R_RNG * G2 * BINS * 4);   // 12.8 MB (was 25.6)
  float* dinv = (float*)take((size_t)N * 4);
  float* p1   = (float*)take(256 * 4);
  float* p2   = (float*)take(256 * 4);
  short* wt1h = (short*)take((size_t)128 * 128 * 2);
  short* wt1l = (short*)take((size_t)128 * 128 * 2);
  short* wt2h = (short*)take((size_t)128 * 128 * 2);
  short* wt2l = (short*)take((size_t)128 * 128 * 2);
  short* wtfh = (short*)take((size_t)128 * 384 * 2);
  short* wtfl = (short*)take((size_t)128 * 384 * 2);
  int2*  cpair= (int2*)take((size_t)E * 8);
  unsigned* cp4 = (unsigned*)take((size_t)E * 4);
  unsigned short* bufH  = (unsigned short*)take((size_t)N * F * 2);  // conv out (gathered)
  unsigned short* bufB16= (unsigned short*)take((size_t)N * F * 2);  // h1 bf16
  unsigned short* bufC16= (unsigned short*)take((size_t)N * F * 2);  // h2 bf16

  // W prep + BN-stats zeroing
  k_wprep_all<<<320, 256, 0, stream>>>(W1, W2, Wf1, wt1h, wt1l, wt2h, wt2l, wtfh, wtfl, st1, st2);

  // partition-based atomic-free CSC build
  k_phist<<<NPB, 256, 0, stream>>>(ei, Psl);
  k_pscatter<<<NPB, 256, 0, stream>>>(ei, ew, Psl, pe);
  k_hist2<<<R_RNG * G2, 256, 0, stream>>>(pe, Psl, Phist);
  k_reduce<<<(N + 255) / 256, 256, 0, stream>>>(Phist, cnt);
  k_bsum<<<NB, 256, 0, stream>>>(cnt, bsum);
  k_bscan<<<1, 128, 0, stream>>>(bsum, bbase, &off[N]);
  k_off<<<NB, 256, 0, stream>>>(cnt, bbase, off);
  k_scatter3<<<R_RNG * G2, 256, 0, stream>>>(pe, Psl, off, Phist, cpair);
  k_degcsc<<<(N + 255) / 256, 256, 0, stream>>>(cpair, off, dinv);
  k_nrm<<<(N + 255) / 256, 256, 0, stream>>>(off, dinv, cpair, cp4);

  const int gemm_grid = (N + 127) / 128;
  // conv1: bufH(bf16) = x @ W1
  k_gemm_mfma<4, true, false, 0><<<gemm_grid, 256, 0, stream>>>(
      x, nullptr, nullptr, nullptr, nullptr, nullptr, wt1h, wt1l, nullptr, bufH, nullptr, nullptr);
  k_agg<<<(N + 3) / 4, 256, 0, stream>>>((const unsigned*)bufH, cp4, off, dinv, b1,
                                         (unsigned*)bufB16);
  k_stats<<<256, 256, 0, stream>>>((const unsigned*)bufB16, st1);
  k_bnparam<<<1, 128, 0, stream>>>(st1, g1, be1, p1);
  // conv2: bufH(bf16) = bn1(h1_bf16) @ W2   (A is bf16)
  k_gemm_mfma<4, true, false, 1><<<gemm_grid, 256, 0, stream>>>(
      bufB16, p1, nullptr, nullptr, nullptr, nullptr, wt2h, wt2l, nullptr, bufH, nullptr, nullptr);
  k_agg<<<(N + 3) / 4, 256, 0, stream>>>((const unsigned*)bufH, cp4, off, dinv, b2,
                                         (unsigned*)bufC16);
  k_stats<<<256, 256, 0, stream>>>((const unsigned*)bufC16, st2);
  k_bnparam<<<1, 128, 0, stream>>>(st2, g2, be2, p2);
  // fc1 + fused fc2 over [x | bn1(h1) | bn2(h2)] -> out[N]  (segs 1,2 bf16)
  k_gemm_mfma<12, false, true, 6><<<gemm_grid, 256, 0, stream>>>(
      x, nullptr, bufB16, p1, bufC16, p2, wtfh, wtfl, bf1, out, Wf2, bf2);
}